// Round 1
// baseline (127.452 us; speedup 1.0000x reference)
//
#include <hip/hip_runtime.h>
#include <math.h>

#define HH 192
#define WW 192
#define NPIX (HH * WW)
#define SCALE 0.25f   // head_dim(16)^-0.5

// ---------------------------------------------------------------------------
// Kernel 1: fused Q/K/V projection.
// x is [C=64][NPIX] (NCHW, B=1). Output q,k,v as [NPIX][64] (= [pixel][h][d]).
// Block = 256 threads handles 64 pixels. x tile staged in LDS.
// lane j = output channel (coalesced weight loads + coalesced stores),
// each thread accumulates 16 pixels.
// ---------------------------------------------------------------------------
__global__ __launch_bounds__(256) void qkv_kernel(
    const float* __restrict__ x,
    const float* __restrict__ wq, const float* __restrict__ wk,
    const float* __restrict__ wv,
    float* __restrict__ q, float* __restrict__ k, float* __restrict__ v)
{
    __shared__ float xs[64 * 64];     // [cin][p]
    const int t = threadIdx.x;
    const int pixel0 = blockIdx.x * 64;
    const int lp  = t & 63;
    const int grp = t >> 6;           // 0..3

    // coalesced load of the 64x64 input tile
    #pragma unroll
    for (int i = 0; i < 16; ++i) {
        const int cin = grp + i * 4;
        xs[cin * 64 + lp] = x[cin * NPIX + pixel0 + lp];
    }
    __syncthreads();

    const int j = t & 63;             // output channel for this lane
    float aq[16], ak[16], av[16];
    #pragma unroll
    for (int pp = 0; pp < 16; ++pp) { aq[pp] = 0.f; ak[pp] = 0.f; av[pp] = 0.f; }

    for (int i = 0; i < 64; ++i) {
        const float wqv = wq[i * 64 + j];
        const float wkv = wk[i * 64 + j];
        const float wvv = wv[i * 64 + j];
        const float4* xr = reinterpret_cast<const float4*>(&xs[i * 64 + grp * 16]);
        #pragma unroll
        for (int p4 = 0; p4 < 4; ++p4) {
            const float4 xv = xr[p4];
            const float xe[4] = { xv.x, xv.y, xv.z, xv.w };
            #pragma unroll
            for (int e = 0; e < 4; ++e) {
                const int pp = p4 * 4 + e;
                aq[pp] = fmaf(xe[e], wqv, aq[pp]);
                ak[pp] = fmaf(xe[e], wkv, ak[pp]);
                av[pp] = fmaf(xe[e], wvv, av[pp]);
            }
        }
    }

    #pragma unroll
    for (int pp = 0; pp < 16; ++pp) {
        const int p = grp * 16 + pp;
        const int row = (pixel0 + p) * 64 + j;
        q[row] = aq[pp];
        k[row] = ak[pp];
        v[row] = av[pp];
    }
}

// ---------------------------------------------------------------------------
// Kernel 2: neighborhood attention with online softmax.
// One thread per (pixel, head). q/k/v are [NPIX][h=4][d=16].
// out may alias q (each thread reads only its own q slice, then writes the
// same slice at the end) -> q/out are NOT __restrict__.
// ---------------------------------------------------------------------------
__global__ __launch_bounds__(256) void attn_kernel(
    const float* q, const float* __restrict__ k, const float* __restrict__ v,
    const float* __restrict__ sims, float* out)
{
    const int g = blockIdx.x * 256 + threadIdx.x;
    const int h = g & 3;
    const int pixel = g >> 2;
    const int y = pixel / WW;
    const int x = pixel - y * WW;

    int sy = y - 3; sy = sy < 0 ? 0 : (sy > HH - 7 ? HH - 7 : sy);
    int sx = x - 3; sx = sx < 0 ? 0 : (sx > WW - 7 ? WW - 7 : sx);
    const int sbase = (y >> 4) * 12 + (x >> 4);   // si*12 + sj

    float4 q0, q1, q2, q3;
    {
        const float4* qp = reinterpret_cast<const float4*>(q + pixel * 64 + h * 16);
        q0 = qp[0]; q1 = qp[1]; q2 = qp[2]; q3 = qp[3];
    }

    float M = -INFINITY, S = 0.f;
    float acc[16];
    #pragma unroll
    for (int d = 0; d < 16; ++d) acc[d] = 0.f;

    for (int ky = 0; ky < 7; ++ky) {
        const int ny = sy + ky;
        #pragma unroll
        for (int kx = 0; kx < 7; ++kx) {
            const int nx = sx + kx;
            const int np = ny * WW + nx;
            const float4* kp = reinterpret_cast<const float4*>(k + np * 64 + h * 16);
            const float4 k0 = kp[0], k1 = kp[1], k2 = kp[2], k3 = kp[3];

            float d0 = q0.x * k0.x, d1 = q0.y * k0.y, d2 = q0.z * k0.z, d3 = q0.w * k0.w;
            d0 = fmaf(q1.x, k1.x, d0); d1 = fmaf(q1.y, k1.y, d1);
            d2 = fmaf(q1.z, k1.z, d2); d3 = fmaf(q1.w, k1.w, d3);
            d0 = fmaf(q2.x, k2.x, d0); d1 = fmaf(q2.y, k2.y, d1);
            d2 = fmaf(q2.z, k2.z, d2); d3 = fmaf(q2.w, k2.w, d3);
            d0 = fmaf(q3.x, k3.x, d0); d1 = fmaf(q3.y, k3.y, d1);
            d2 = fmaf(q3.z, k3.z, d2); d3 = fmaf(q3.w, k3.w, d3);
            const float dot = (d0 + d1) + (d2 + d3);

            const float m = sims[np * 144 + sbase];
            const float s = SCALE * dot * m;
            const float newM = fmaxf(M, s);
            const float cf = __expf(M - newM);   // exp(-inf)=0 on first iter
            const float pf = __expf(s - newM);
            S = S * cf + pf;
            const float pm = pf * m;

            const float4* vp = reinterpret_cast<const float4*>(v + np * 64 + h * 16);
            const float4 v0 = vp[0], v1 = vp[1], v2 = vp[2], v3 = vp[3];
            acc[0]  = fmaf(acc[0],  cf, pm * v0.x);
            acc[1]  = fmaf(acc[1],  cf, pm * v0.y);
            acc[2]  = fmaf(acc[2],  cf, pm * v0.z);
            acc[3]  = fmaf(acc[3],  cf, pm * v0.w);
            acc[4]  = fmaf(acc[4],  cf, pm * v1.x);
            acc[5]  = fmaf(acc[5],  cf, pm * v1.y);
            acc[6]  = fmaf(acc[6],  cf, pm * v1.z);
            acc[7]  = fmaf(acc[7],  cf, pm * v1.w);
            acc[8]  = fmaf(acc[8],  cf, pm * v2.x);
            acc[9]  = fmaf(acc[9],  cf, pm * v2.y);
            acc[10] = fmaf(acc[10], cf, pm * v2.z);
            acc[11] = fmaf(acc[11], cf, pm * v2.w);
            acc[12] = fmaf(acc[12], cf, pm * v3.x);
            acc[13] = fmaf(acc[13], cf, pm * v3.y);
            acc[14] = fmaf(acc[14], cf, pm * v3.z);
            acc[15] = fmaf(acc[15], cf, pm * v3.w);
            M = newM;
        }
    }

    const float inv = 1.f / S;
    float4* op = reinterpret_cast<float4*>(out + pixel * 64 + h * 16);
    op[0] = make_float4(acc[0] * inv,  acc[1] * inv,  acc[2] * inv,  acc[3] * inv);
    op[1] = make_float4(acc[4] * inv,  acc[5] * inv,  acc[6] * inv,  acc[7] * inv);
    op[2] = make_float4(acc[8] * inv,  acc[9] * inv,  acc[10] * inv, acc[11] * inv);
    op[3] = make_float4(acc[12] * inv, acc[13] * inv, acc[14] * inv, acc[15] * inv);
}

// ---------------------------------------------------------------------------
// Kernel 3: output projection + transpose to NCHW.
// ain is [NPIX][64]; out is [C=64][NPIX].
// Block = 256 threads handles 64 pixels; tile transposed through LDS
// (stride-65 pad), lane = pixel -> coalesced stores; w_proj reads are
// wave-uniform -> scalar loads.
// ---------------------------------------------------------------------------
__global__ __launch_bounds__(256) void proj_kernel(
    const float* __restrict__ ain, const float* __restrict__ wp,
    float* __restrict__ out)
{
    __shared__ float xs[64 * 65];     // [cin][p], padded
    const int t = threadIdx.x;
    const int pixel0 = blockIdx.x * 64;

    #pragma unroll
    for (int i = 0; i < 16; ++i) {
        const int l = i * 256 + t;    // 0..4095
        const int p = l >> 6;
        const int cin = l & 63;
        xs[cin * 65 + p] = ain[pixel0 * 64 + l];
    }
    __syncthreads();

    const int p = t & 63;
    const int grp = t >> 6;
    float acc[16];
    #pragma unroll
    for (int cc = 0; cc < 16; ++cc) acc[cc] = 0.f;

    for (int i = 0; i < 64; ++i) {
        const float xv = xs[i * 65 + p];
        #pragma unroll
        for (int cc = 0; cc < 16; ++cc) {
            const int c = grp + cc * 4;
            acc[cc] = fmaf(xv, wp[i * 64 + c], acc[cc]);
        }
    }

    #pragma unroll
    for (int cc = 0; cc < 16; ++cc) {
        const int c = grp + cc * 4;
        out[c * NPIX + pixel0 + p] = acc[cc];
    }
}

// ---------------------------------------------------------------------------
extern "C" void kernel_launch(void* const* d_in, const int* in_sizes, int n_in,
                              void* d_out, int out_size, void* d_ws, size_t ws_size,
                              hipStream_t stream)
{
    const float* x    = (const float*)d_in[0];
    const float* sims = (const float*)d_in[1];
    const float* wq   = (const float*)d_in[2];
    const float* wk   = (const float*)d_in[3];
    const float* wv   = (const float*)d_in[4];
    const float* wp   = (const float*)d_in[5];
    float* out = (float*)d_out;

    float* q = (float*)d_ws;                  // [NPIX][64]
    float* k = q + (size_t)NPIX * 64;
    float* v = k + (size_t)NPIX * 64;
    // attention output reuses the q buffer (safe: 1:1 read-then-write per thread)

    qkv_kernel<<<NPIX / 64, 256, 0, stream>>>(x, wq, wk, wv, q, k, v);
    attn_kernel<<<NPIX * 4 / 256, 256, 0, stream>>>(q, k, v, sims, q);
    proj_kernel<<<NPIX / 64, 256, 0, stream>>>(q, wp, out);
}

// Round 2
// 112.869 us; speedup vs baseline: 1.1292x; 1.1292x over previous
//
#include <hip/hip_runtime.h>
#include <math.h>

#define HH 192
#define WW 192
#define NPIX (HH * WW)
#define SCALE 0.25f   // head_dim(16)^-0.5

// ---------------------------------------------------------------------------
// Kernel 1: fused Q/K/V projection.
// x is [C=64][NPIX]. Output q,k,v as [NPIX][64] (= [pixel][h][d]).
// Block = 256 threads handles 32 pixels (1152 blocks -> 18 waves/CU).
// lane j = output channel; each thread accumulates 8 pixels.
// ---------------------------------------------------------------------------
__global__ __launch_bounds__(256) void qkv_kernel(
    const float* __restrict__ x,
    const float* __restrict__ wq, const float* __restrict__ wk,
    const float* __restrict__ wv,
    float* __restrict__ q, float* __restrict__ k, float* __restrict__ v)
{
    __shared__ float xs[64 * 32];     // [cin][p]
    const int t = threadIdx.x;
    const int pixel0 = blockIdx.x * 32;

    // coalesced load of the 64x32 input tile
    #pragma unroll
    for (int i = 0; i < 8; ++i) {
        const int l = i * 256 + t;    // 0..2047
        const int cin = l >> 5;
        const int p = l & 31;
        xs[cin * 32 + p] = x[cin * NPIX + pixel0 + p];
    }
    __syncthreads();

    const int j = t & 63;             // output channel for this lane
    const int grp = t >> 6;           // 0..3 -> pixels grp*8 .. grp*8+7
    float aq[8], ak[8], av[8];
    #pragma unroll
    for (int pp = 0; pp < 8; ++pp) { aq[pp] = 0.f; ak[pp] = 0.f; av[pp] = 0.f; }

    for (int i = 0; i < 64; ++i) {
        const float wqv = wq[i * 64 + j];
        const float wkv = wk[i * 64 + j];
        const float wvv = wv[i * 64 + j];
        const float4* xr = reinterpret_cast<const float4*>(&xs[i * 32 + grp * 8]);
        #pragma unroll
        for (int p4 = 0; p4 < 2; ++p4) {
            const float4 xv = xr[p4];
            const float xe[4] = { xv.x, xv.y, xv.z, xv.w };
            #pragma unroll
            for (int e = 0; e < 4; ++e) {
                const int pp = p4 * 4 + e;
                aq[pp] = fmaf(xe[e], wqv, aq[pp]);
                ak[pp] = fmaf(xe[e], wkv, ak[pp]);
                av[pp] = fmaf(xe[e], wvv, av[pp]);
            }
        }
    }

    #pragma unroll
    for (int pp = 0; pp < 8; ++pp) {
        const int p = grp * 8 + pp;
        const int row = (pixel0 + p) * 64 + j;
        q[row] = aq[pp];
        k[row] = ak[pp];
        v[row] = av[pp];
    }
}

// ---------------------------------------------------------------------------
// Kernel 2: neighborhood attention, NO-max softmax (logits bounded; softmax is
// shift-invariant), neighbor set split across an even/odd lane pair.
// Thread g: half = g&1, h = (g>>1)&3, pixel = g>>3. 1152 blocks of 256.
// out may alias q (pair reads only its own q slice, writes same slice at end).
// ---------------------------------------------------------------------------
__global__ __launch_bounds__(256, 4) void attn_kernel(
    const float* q, const float* __restrict__ k, const float* __restrict__ v,
    const float* __restrict__ sims, float* out)
{
    const int g = blockIdx.x * 256 + threadIdx.x;
    const int half  = g & 1;
    const int h     = (g >> 1) & 3;
    const int pixel = g >> 3;
    const int y = pixel / WW;
    const int x = pixel - y * WW;

    int sy = y - 3; sy = sy < 0 ? 0 : (sy > HH - 7 ? HH - 7 : sy);
    int sx = x - 3; sx = sx < 0 ? 0 : (sx > WW - 7 ? WW - 7 : sx);
    const int sbase = (y >> 4) * 12 + (x >> 4);   // si*12 + sj
    const int rowbase = sy * WW + sx;

    float4 q0, q1, q2, q3;
    {
        const float4* qp = reinterpret_cast<const float4*>(q + pixel * 64 + h * 16);
        q0 = qp[0]; q1 = qp[1]; q2 = qp[2]; q3 = qp[3];
    }

    float S = 0.f;
    float acc[16];
    #pragma unroll
    for (int d = 0; d < 16; ++d) acc[d] = 0.f;

    // neighbors nn = 2*i + half, nn in [0,49): independent iterations
    #pragma unroll
    for (int i = 0; i < 25; ++i) {
        const int nn = 2 * i + half;
        if (nn < 49) {
            const int ky = (nn * 37) >> 8;        // nn/7 for nn<56
            const int kx = nn - 7 * ky;
            const int np = rowbase + ky * WW + kx;

            const float m = sims[np * 144 + sbase];
            const float4* kp = reinterpret_cast<const float4*>(k + np * 64 + h * 16);
            const float4 k0 = kp[0], k1 = kp[1], k2 = kp[2], k3 = kp[3];

            float d0 = q0.x * k0.x, d1 = q0.y * k0.y, d2 = q0.z * k0.z, d3 = q0.w * k0.w;
            d0 = fmaf(q1.x, k1.x, d0); d1 = fmaf(q1.y, k1.y, d1);
            d2 = fmaf(q1.z, k1.z, d2); d3 = fmaf(q1.w, k1.w, d3);
            d0 = fmaf(q2.x, k2.x, d0); d1 = fmaf(q2.y, k2.y, d1);
            d2 = fmaf(q2.z, k2.z, d2); d3 = fmaf(q2.w, k2.w, d3);
            d0 = fmaf(q3.x, k3.x, d0); d1 = fmaf(q3.y, k3.y, d1);
            d2 = fmaf(q3.z, k3.z, d2); d3 = fmaf(q3.w, k3.w, d3);
            const float dot = (d0 + d1) + (d2 + d3);

            const float pf = __expf(SCALE * dot * m);
            S += pf;
            const float pm = pf * m;

            const float4* vp = reinterpret_cast<const float4*>(v + np * 64 + h * 16);
            const float4 v0 = vp[0], v1 = vp[1], v2 = vp[2], v3 = vp[3];
            acc[0]  = fmaf(pm, v0.x, acc[0]);
            acc[1]  = fmaf(pm, v0.y, acc[1]);
            acc[2]  = fmaf(pm, v0.z, acc[2]);
            acc[3]  = fmaf(pm, v0.w, acc[3]);
            acc[4]  = fmaf(pm, v1.x, acc[4]);
            acc[5]  = fmaf(pm, v1.y, acc[5]);
            acc[6]  = fmaf(pm, v1.z, acc[6]);
            acc[7]  = fmaf(pm, v1.w, acc[7]);
            acc[8]  = fmaf(pm, v2.x, acc[8]);
            acc[9]  = fmaf(pm, v2.y, acc[9]);
            acc[10] = fmaf(pm, v2.z, acc[10]);
            acc[11] = fmaf(pm, v2.w, acc[11]);
            acc[12] = fmaf(pm, v3.x, acc[12]);
            acc[13] = fmaf(pm, v3.y, acc[13]);
            acc[14] = fmaf(pm, v3.z, acc[14]);
            acc[15] = fmaf(pm, v3.w, acc[15]);
        }
    }

    // combine the even/odd pair: 16 acc + S via shfl_xor(1)
    float S2 = S + __shfl_xor(S, 1, 64);
    float comb[16];
    #pragma unroll
    for (int j = 0; j < 16; ++j)
        comb[j] = acc[j] + __shfl_xor(acc[j], 1, 64);

    const float inv = 1.f / S2;
    float* ob = out + pixel * 64 + h * 16 + half * 8;   // contiguous across block
    float4* op = reinterpret_cast<float4*>(ob);
    if (half == 0) {
        op[0] = make_float4(comb[0] * inv, comb[1] * inv, comb[2] * inv, comb[3] * inv);
        op[1] = make_float4(comb[4] * inv, comb[5] * inv, comb[6] * inv, comb[7] * inv);
    } else {
        op[0] = make_float4(comb[8] * inv,  comb[9] * inv,  comb[10] * inv, comb[11] * inv);
        op[1] = make_float4(comb[12] * inv, comb[13] * inv, comb[14] * inv, comb[15] * inv);
    }
}

// ---------------------------------------------------------------------------
// Kernel 3: output projection + transpose to NCHW.
// ain is [NPIX][64]; out is [C=64][NPIX].
// Block = 256 threads handles 32 pixels (1152 blocks). LDS-transposed tile,
// lane = pixel (32) x 8 cout-groups -> coalesced stores.
// ---------------------------------------------------------------------------
__global__ __launch_bounds__(256) void proj_kernel(
    const float* __restrict__ ain, const float* __restrict__ wp,
    float* __restrict__ out)
{
    __shared__ float xs[64 * 33];     // [cin][p], padded
    const int t = threadIdx.x;
    const int pixel0 = blockIdx.x * 32;

    #pragma unroll
    for (int i = 0; i < 8; ++i) {
        const int l = i * 256 + t;    // 0..2047
        const int p = l >> 6;         // pixel in tile
        const int cin = l & 63;
        xs[cin * 33 + p] = ain[(pixel0 + p) * 64 + cin];
    }
    __syncthreads();

    const int p = t & 31;
    const int grp = t >> 5;           // 0..7 -> couts grp*8 .. grp*8+7
    float acc[8];
    #pragma unroll
    for (int cc = 0; cc < 8; ++cc) acc[cc] = 0.f;

    for (int i = 0; i < 64; ++i) {
        const float xv = xs[i * 33 + p];
        #pragma unroll
        for (int cc = 0; cc < 8; ++cc) {
            acc[cc] = fmaf(xv, wp[i * 64 + grp * 8 + cc], acc[cc]);
        }
    }

    #pragma unroll
    for (int cc = 0; cc < 8; ++cc) {
        const int c = grp * 8 + cc;
        out[c * NPIX + pixel0 + p] = acc[cc];
    }
}

// ---------------------------------------------------------------------------
extern "C" void kernel_launch(void* const* d_in, const int* in_sizes, int n_in,
                              void* d_out, int out_size, void* d_ws, size_t ws_size,
                              hipStream_t stream)
{
    const float* x    = (const float*)d_in[0];
    const float* sims = (const float*)d_in[1];
    const float* wq   = (const float*)d_in[2];
    const float* wk   = (const float*)d_in[3];
    const float* wv   = (const float*)d_in[4];
    const float* wp   = (const float*)d_in[5];
    float* out = (float*)d_out;

    float* q = (float*)d_ws;                  // [NPIX][64]
    float* k = q + (size_t)NPIX * 64;
    float* v = k + (size_t)NPIX * 64;
    // attention output reuses the q buffer (safe: pair reads only its own q
    // slice before the pair writes that same slice)

    qkv_kernel<<<NPIX / 32, 256, 0, stream>>>(x, wq, wk, wv, q, k, v);
    attn_kernel<<<NPIX * 8 / 256, 256, 0, stream>>>(q, k, v, sims, q);
    proj_kernel<<<NPIX / 32, 256, 0, stream>>>(q, wp, out);
}

// Round 3
// 55.121 us; speedup vs baseline: 2.3122x; 2.0477x over previous
//
#include <hip/hip_runtime.h>
#include <hip/hip_bf16.h>
#include <math.h>

#define HH 192
#define WW 192
#define NPIX (HH * WW)
#define SCALE 0.25f   // head_dim(16)^-0.5

// per-head LDS region stride in dwords: 196 neighbors * 8 dwords + 4 pad
// (pad=4 -> region stride mod 32 = 4 -> b128 reads spread to the
//  8-accesses-per-bank floor instead of 16-way conflicts)
#define REG 1572

__device__ __forceinline__ float blo(unsigned int w) { return __uint_as_float(w << 16); }
__device__ __forceinline__ float bhi(unsigned int w) { return __uint_as_float(w & 0xffff0000u); }

// ---------------------------------------------------------------------------
// Kernel 1: fused Q/K/V projection.
// x is [C=64][NPIX]. q out f32 [NPIX][64]; k,v out bf16 [NPIX][64].
// ---------------------------------------------------------------------------
__global__ __launch_bounds__(256) void qkv_kernel(
    const float* __restrict__ x,
    const float* __restrict__ wq, const float* __restrict__ wk,
    const float* __restrict__ wv,
    float* __restrict__ q, __hip_bfloat16* __restrict__ kg,
    __hip_bfloat16* __restrict__ vg)
{
    __shared__ float xs[64 * 32];     // [cin][p]
    const int t = threadIdx.x;
    const int pixel0 = blockIdx.x * 32;

    #pragma unroll
    for (int i = 0; i < 8; ++i) {
        const int l = i * 256 + t;
        const int cin = l >> 5;
        const int p = l & 31;
        xs[cin * 32 + p] = x[cin * NPIX + pixel0 + p];
    }
    __syncthreads();

    const int j = t & 63;             // output channel
    const int grp = t >> 6;           // 0..3 -> pixels grp*8 .. grp*8+7
    float aq[8], ak[8], av[8];
    #pragma unroll
    for (int pp = 0; pp < 8; ++pp) { aq[pp] = 0.f; ak[pp] = 0.f; av[pp] = 0.f; }

    for (int i = 0; i < 64; ++i) {
        const float wqv = wq[i * 64 + j];
        const float wkv = wk[i * 64 + j];
        const float wvv = wv[i * 64 + j];
        const float4* xr = reinterpret_cast<const float4*>(&xs[i * 32 + grp * 8]);
        #pragma unroll
        for (int p4 = 0; p4 < 2; ++p4) {
            const float4 xv = xr[p4];
            const float xe[4] = { xv.x, xv.y, xv.z, xv.w };
            #pragma unroll
            for (int e = 0; e < 4; ++e) {
                const int pp = p4 * 4 + e;
                aq[pp] = fmaf(xe[e], wqv, aq[pp]);
                ak[pp] = fmaf(xe[e], wkv, ak[pp]);
                av[pp] = fmaf(xe[e], wvv, av[pp]);
            }
        }
    }

    #pragma unroll
    for (int pp = 0; pp < 8; ++pp) {
        const int row = (pixel0 + grp * 8 + pp) * 64 + j;
        q[row]  = aq[pp];
        kg[row] = __float2bfloat16(ak[pp]);
        vg[row] = __float2bfloat16(av[pp]);
    }
}

// ---------------------------------------------------------------------------
// Kernel 2: tiled neighborhood attention + fused output projection.
// Block = 8x8 pixel tile x 4 heads = 256 threads. 576 blocks, XCD-swizzled
// so each XCD owns 3 contiguous tile rows (working set ~= its 4MB L2).
// Stage k,v halo (14x14 pixels, bf16, per-head regions) + sims in LDS.
// Then project through LDS (attn-out transposed) and store NCHW.
// ---------------------------------------------------------------------------
__global__ __launch_bounds__(256, 3) void attn_proj_kernel(
    const float* __restrict__ q,
    const __hip_bfloat16* __restrict__ kg,
    const __hip_bfloat16* __restrict__ vg,
    const float* __restrict__ sims,
    const float* __restrict__ wp,
    float* __restrict__ out)
{
    __shared__ unsigned int smem[8 * REG + 256];   // k[4][REG], v[4][REG], sims[196]

    const int bid = blockIdx.x;
    const int tl = (bid & 7) * 72 + (bid >> 3);    // XCD swizzle (576 = 8*72)
    const int ty = tl / 24, tx = tl - ty * 24;
    const int Y0 = ty * 8, X0 = tx * 8;
    int hy0 = Y0 - 3; hy0 = hy0 < 0 ? 0 : (hy0 > HH - 14 ? HH - 14 : hy0);
    int hx0 = X0 - 3; hx0 = hx0 < 0 ? 0 : (hx0 > WW - 14 ? WW - 14 : hx0);
    const int t = threadIdx.x;

    // ---- stage k,v halo: 196 pixel rows of 128B each = 1568 dwordx4 units/tensor
    {
        const unsigned int* kgw = reinterpret_cast<const unsigned int*>(kg);
        const unsigned int* vgw = reinterpret_cast<const unsigned int*>(vg);
        #pragma unroll
        for (int i = 0; i < 7; ++i) {
            const int idx = i * 256 + t;
            if (idx < 1568) {
                const int hidx = idx >> 3;        // halo pixel 0..195
                const int u = idx & 7;            // dwordx4 unit within 128B row
                const int r = hidx / 14;
                const int c = hidx - r * 14;
                const int np = (hy0 + r) * WW + hx0 + c;
                const uint4 kk = *reinterpret_cast<const uint4*>(kgw + np * 32 + u * 4);
                const uint4 vv = *reinterpret_cast<const uint4*>(vgw + np * 32 + u * 4);
                const int h = u >> 1, hf = u & 1;
                unsigned int* dk = smem + h * REG + hidx * 8 + hf * 4;
                *reinterpret_cast<uint4*>(dk) = kk;
                *reinterpret_cast<uint4*>(dk + 4 * REG) = vv;
            }
        }
        if (t < 196) {
            const int r = t / 14;
            const int c = t - r * 14;
            const int np = (hy0 + r) * WW + hx0 + c;
            const int sbase = (Y0 >> 4) * 12 + (X0 >> 4);   // block-uniform
            reinterpret_cast<float*>(smem)[8 * REG + t] = sims[np * 144 + sbase];
        }
    }
    __syncthreads();

    // ---- attention main loop
    const int p = t >> 2, h = t & 3;
    const int py = p >> 3, px = p & 7;
    const int y = Y0 + py, xq = X0 + px;
    int sy = y - 3; sy = sy < 0 ? 0 : (sy > HH - 7 ? HH - 7 : sy);
    int sx = xq - 3; sx = sx < 0 ? 0 : (sx > WW - 7 ? WW - 7 : sx);
    const int wbase = (sy - hy0) * 14 + (sx - hx0);

    float4 q0, q1, q2, q3;
    {
        const float4* qp = reinterpret_cast<const float4*>(q + (y * WW + xq) * 64 + h * 16);
        q0 = qp[0]; q1 = qp[1]; q2 = qp[2]; q3 = qp[3];
    }

    const unsigned int* kreg = smem + h * REG;
    const unsigned int* vreg = kreg + 4 * REG;
    const float* sm = reinterpret_cast<const float*>(smem + 8 * REG);

    float S = 0.f;
    float acc[16];
    #pragma unroll
    for (int d = 0; d < 16; ++d) acc[d] = 0.f;

    #pragma unroll 1
    for (int ky = 0; ky < 7; ++ky) {
        #pragma unroll
        for (int kx = 0; kx < 7; ++kx) {
            const int hidx = wbase + ky * 14 + kx;
            const uint4 ka = *reinterpret_cast<const uint4*>(kreg + hidx * 8);
            const uint4 k2 = *reinterpret_cast<const uint4*>(kreg + hidx * 8 + 4);

            float d0 = q0.x * blo(ka.x), d1 = q0.y * bhi(ka.x);
            float d2 = q0.z * blo(ka.y), d3 = q0.w * bhi(ka.y);
            d0 = fmaf(q1.x, blo(ka.z), d0); d1 = fmaf(q1.y, bhi(ka.z), d1);
            d2 = fmaf(q1.z, blo(ka.w), d2); d3 = fmaf(q1.w, bhi(ka.w), d3);
            d0 = fmaf(q2.x, blo(k2.x), d0); d1 = fmaf(q2.y, bhi(k2.x), d1);
            d2 = fmaf(q2.z, blo(k2.y), d2); d3 = fmaf(q2.w, bhi(k2.y), d3);
            d0 = fmaf(q3.x, blo(k2.z), d0); d1 = fmaf(q3.y, bhi(k2.z), d1);
            d2 = fmaf(q3.z, blo(k2.w), d2); d3 = fmaf(q3.w, bhi(k2.w), d3);
            const float dot = (d0 + d1) + (d2 + d3);

            const float m = sm[hidx];
            const float pf = __expf(SCALE * dot * m);
            S += pf;
            const float pm = pf * m;

            const uint4 va = *reinterpret_cast<const uint4*>(vreg + hidx * 8);
            const uint4 v2 = *reinterpret_cast<const uint4*>(vreg + hidx * 8 + 4);
            acc[0]  = fmaf(pm, blo(va.x), acc[0]);
            acc[1]  = fmaf(pm, bhi(va.x), acc[1]);
            acc[2]  = fmaf(pm, blo(va.y), acc[2]);
            acc[3]  = fmaf(pm, bhi(va.y), acc[3]);
            acc[4]  = fmaf(pm, blo(va.z), acc[4]);
            acc[5]  = fmaf(pm, bhi(va.z), acc[5]);
            acc[6]  = fmaf(pm, blo(va.w), acc[6]);
            acc[7]  = fmaf(pm, bhi(va.w), acc[7]);
            acc[8]  = fmaf(pm, blo(v2.x), acc[8]);
            acc[9]  = fmaf(pm, bhi(v2.x), acc[9]);
            acc[10] = fmaf(pm, blo(v2.y), acc[10]);
            acc[11] = fmaf(pm, bhi(v2.y), acc[11]);
            acc[12] = fmaf(pm, blo(v2.z), acc[12]);
            acc[13] = fmaf(pm, bhi(v2.z), acc[13]);
            acc[14] = fmaf(pm, blo(v2.w), acc[14]);
            acc[15] = fmaf(pm, bhi(v2.w), acc[15]);
        }
    }
    const float inv = 1.f / S;

    // ---- fused projection: bounce attn-out through LDS transposed
    __syncthreads();                   // all LDS reads of k/v/sims done
    float* os = reinterpret_cast<float*>(smem);   // [64 ch][65] (pad)
    #pragma unroll
    for (int jj = 0; jj < 16; ++jj)
        os[(h * 16 + jj) * 65 + p] = acc[jj] * inv;
    __syncthreads();

    const int pix2 = t & 63;                           // pixel in tile
    const int cg = __builtin_amdgcn_readfirstlane(t >> 6);  // wave-uniform cout group
    float o2[16];
    #pragma unroll
    for (int cc = 0; cc < 16; ++cc) o2[cc] = 0.f;

    for (int cin = 0; cin < 64; ++cin) {
        const float xv = os[cin * 65 + pix2];
        #pragma unroll
        for (int cc = 0; cc < 16; ++cc)
            o2[cc] = fmaf(xv, wp[cin * 64 + cg * 16 + cc], o2[cc]);
    }

    const int gy = Y0 + (pix2 >> 3), gx = X0 + (pix2 & 7);
    #pragma unroll
    for (int cc = 0; cc < 16; ++cc)
        out[(cg * 16 + cc) * NPIX + gy * WW + gx] = o2[cc];
}

// ---------------------------------------------------------------------------
extern "C" void kernel_launch(void* const* d_in, const int* in_sizes, int n_in,
                              void* d_out, int out_size, void* d_ws, size_t ws_size,
                              hipStream_t stream)
{
    const float* x    = (const float*)d_in[0];
    const float* sims = (const float*)d_in[1];
    const float* wq   = (const float*)d_in[2];
    const float* wk   = (const float*)d_in[3];
    const float* wv   = (const float*)d_in[4];
    const float* wp   = (const float*)d_in[5];
    float* out = (float*)d_out;

    float* q = (float*)d_ws;                                   // f32 [NPIX][64]
    __hip_bfloat16* kg = (__hip_bfloat16*)(q + (size_t)NPIX * 64);
    __hip_bfloat16* vg = kg + (size_t)NPIX * 64;

    qkv_kernel<<<NPIX / 32, 256, 0, stream>>>(x, wq, wk, wv, q, kg, vg);
    attn_proj_kernel<<<576, 256, 0, stream>>>(q, kg, vg, sims, wp, out);
}